// Round 20
// baseline (150.521 us; speedup 1.0000x reference)
//
#include <hip/hip_runtime.h>

typedef unsigned short u16;
typedef unsigned int u32;
typedef __bf16 bf16x8 __attribute__((ext_vector_type(8)));
typedef float f32x4 __attribute__((ext_vector_type(4)));
typedef float f32x16 __attribute__((ext_vector_type(16)));

#define SCALE_QK 0.35355339059327373f  // 64^-0.25
#define LOG2E 1.4426950408889634f

__device__ __forceinline__ u16 f2bf(float f) {
  u32 u = __float_as_uint(f);
  u += 0x7FFFu + ((u >> 16) & 1u);
  return (u16)(u >> 16);
}

__device__ __forceinline__ void gload16(const u16* g, u16* l) {
  __builtin_amdgcn_global_load_lds((const __attribute__((address_space(1))) void*)g,
                                   (__attribute__((address_space(3))) void*)l, 16, 0, 0);
}

// row swizzle, measured conflict-free for 32-consecutive-row b128 reads at 128B rows (r7: 0)
__device__ __forceinline__ int rswz(int r) { return (r & 7) ^ ((r >> 3) & 3); }

// ---------------- fused prologue: weight converts + GroupNorm in ONE launch ----------------
__global__ __launch_bounds__(256) void k_prep(const float* __restrict__ x,
                                              const float* __restrict__ nw,
                                              const float* __restrict__ nb,
                                              const float* __restrict__ qkvw_f,
                                              const float* __restrict__ projw_f,
                                              u16* __restrict__ gnt,
                                              u16* __restrict__ qkvw,
                                              u16* __restrict__ projw) {
  const int bid = blockIdx.x;
  const int tid = threadIdx.x;

  if (bid >= 512) {
    const float* src = (bid < 1280) ? qkvw_f : projw_f;
    u16* dst = (bid < 1280) ? qkvw : projw;
    const int i = (bid - ((bid < 1280) ? 512 : 1280)) * 256 + tid;
    float4 v = ((const float4*)src)[i];
    u32 lo = (u32)f2bf(v.x) | ((u32)f2bf(v.y) << 16);
    u32 hi = (u32)f2bf(v.z) | ((u32)f2bf(v.w) << 16);
    ((uint2*)dst)[i] = make_uint2(lo, hi);
    return;
  }

  const int b = bid >> 5;
  const int g = bid & 31;
  const float* xg = x + ((size_t)b * 512 + g * 16) * 1024;

  float s = 0.f, ss = 0.f;
#pragma unroll
  for (int it = 0; it < 16; ++it) {
    float4 v = ((const float4*)xg)[tid + it * 256];
    s += v.x + v.y + v.z + v.w;
    ss += v.x * v.x + v.y * v.y + v.z * v.z + v.w * v.w;
  }
#pragma unroll
  for (int off = 32; off >= 1; off >>= 1) {
    s += __shfl_xor(s, off);
    ss += __shfl_xor(ss, off);
  }
  __shared__ float red[8];
  const int wid = tid >> 6, lane = tid & 63;
  if (lane == 0) { red[wid] = s; red[4 + wid] = ss; }
  __syncthreads();
  const float mean = (red[0] + red[1] + red[2] + red[3]) * (1.f / 16384.f);
  const float ex2 = (red[4] + red[5] + red[6] + red[7]) * (1.f / 16384.f);
  const float rstd = rsqrtf(ex2 - mean * mean + 1e-5f);

  const int cp = (tid & 7) * 2, tt = tid >> 3;
  const int c0 = g * 16 + cp;
  const float wc0 = nw[c0] * rstd, bc0 = nb[c0] - mean * wc0;
  const float wc1 = nw[c0 + 1] * rstd, bc1 = nb[c0 + 1] - mean * wc1;
  const float* xc0 = xg + (size_t)cp * 1024;
  const float* xc1 = xc0 + 1024;
  u16* dst = gnt + (size_t)b * 1024 * 512 + c0;
#pragma unroll 8
  for (int t = tt; t < 1024; t += 32) {
    const u32 v0 = f2bf(xc0[t] * wc0 + bc0);
    const u32 v1 = f2bf(xc1[t] * wc1 + bc1);
    *(u32*)(dst + (size_t)t * 512) = v0 | (v1 << 16);
  }
}

// ---------------- GEMM (r15 best-measured): BK=64, counted vmcnt(4), wide-store epilogue ---
template <int MODE>
__global__ __launch_bounds__(512) void k_gemm(const u16* __restrict__ A,
                                              const u16* __restrict__ Bw,
                                              const float* __restrict__ bias,
                                              u16* __restrict__ Qb, u16* __restrict__ Kb,
                                              u16* __restrict__ Vb,
                                              const float* __restrict__ xres,
                                              float* __restrict__ out) {
  __shared__ u16 smem[32768];
  u16* Asb = smem;
  u16* Bsb = smem + 16384;
  const int tid = threadIdx.x;
  const int lane = tid & 63, wid = tid >> 6;
  const int wr = wid >> 1, wc = wid & 1;
  const int fid = blockIdx.x;
  const int m0 = (fid & 127) * 128;
  const int n0 = (fid >> 7) * 128;
  const int l15 = lane & 15, l4 = lane >> 4;
  const f32x4 fzero = {0.f, 0.f, 0.f, 0.f};

  f32x4 acc[2][4];
#pragma unroll
  for (int i = 0; i < 2; ++i)
#pragma unroll
    for (int j = 0; j < 4; ++j) acc[i][j] = fzero;

  const int lrow = (tid & 63) >> 3;
  const int lchunk = tid & 7;

  auto stage = [&](int bi, int kt) {
#pragma unroll
    for (int rd = 0; rd < 2; ++rd) {
      const int rbase = wid * 8 + rd * 64;
      const int r = rbase + lrow;
      const int q = lchunk ^ (r & 7);
      gload16(A + ((size_t)(m0 + r) * 512 + kt * 64 + q * 8), Asb + bi * 8192 + rbase * 64);
      gload16(Bw + ((size_t)(n0 + r) * 512 + kt * 64 + q * 8), Bsb + bi * 8192 + rbase * 64);
    }
  };

  stage(0, 0);
  stage(1, 1);

  for (int kt = 0; kt < 8; ++kt) {
    if (kt < 7) {
      asm volatile("s_waitcnt vmcnt(4)" ::: "memory");
    } else {
      asm volatile("s_waitcnt vmcnt(0)" ::: "memory");
    }
    __builtin_amdgcn_s_barrier();
    const int buf = kt & 1;
#pragma unroll
    for (int ks = 0; ks < 2; ++ks) {
      bf16x8 af[2], bfr[4];
#pragma unroll
      for (int mi = 0; mi < 2; ++mi) {
        const int row = wr * 32 + mi * 16 + l15;
        af[mi] = *(const bf16x8*)&Asb[buf * 8192 + row * 64 + (((((ks << 2) + l4)) ^ (row & 7)) << 3)];
      }
#pragma unroll
      for (int ni = 0; ni < 4; ++ni) {
        const int row = wc * 64 + ni * 16 + l15;
        bfr[ni] = *(const bf16x8*)&Bsb[buf * 8192 + row * 64 + (((((ks << 2) + l4)) ^ (row & 7)) << 3)];
      }
#pragma unroll
      for (int mi = 0; mi < 2; ++mi)
#pragma unroll
        for (int ni = 0; ni < 4; ++ni)
          acc[mi][ni] = __builtin_amdgcn_mfma_f32_16x16x32_bf16(af[mi], bfr[ni], acc[mi][ni], 0, 0, 0);
    }
    asm volatile("s_waitcnt lgkmcnt(0)" ::: "memory");
    __builtin_amdgcn_sched_barrier(0);
    __builtin_amdgcn_s_barrier();
    if (kt < 6) stage(buf, kt + 2);
  }

  if (MODE == 0) {
    const int oseg = n0 + wc * 64;
    const int h = oseg / 192;
    const int typ = (oseg - h * 192) >> 6;
    const int b = m0 >> 10;
    const int bh = b * 8 + h;
    const int t0w = (m0 & 1023) + wr * 32;
    if (typ < 2) {
      const float sc = (typ == 0) ? (SCALE_QK * LOG2E) : SCALE_QK;
      u16* scr = smem + wid * 4096;
#pragma unroll
      for (int ni = 0; ni < 4; ++ni) {
        const int ol = ni * 16 + l15;
        const float bo = bias[oseg + ol];
#pragma unroll
        for (int mi = 0; mi < 2; ++mi) {
#pragma unroll
          for (int jj = 0; jj < 4; ++jj) {
            const int tl = mi * 16 + l4 * 4 + jj;
            scr[tl * 72 + ol] = f2bf((acc[mi][ni][jj] + bo) * sc);
          }
        }
      }
      asm volatile("s_waitcnt lgkmcnt(0)" ::: "memory");
      u16* qk = (typ == 0) ? Qb : Kb;
      const int tr = lane & 31;
#pragma unroll
      for (int i = 0; i < 4; ++i) {
        const int ch = (lane >> 5) * 4 + i;
        const uint4 v = *(const uint4*)&scr[tr * 72 + ch * 8];
        *(uint4*)(qk + (((size_t)bh * 1024 + t0w + tr) << 6) + ch * 8) = v;
      }
    } else {
#pragma unroll
      for (int ni = 0; ni < 4; ++ni) {
        const int ci = ni * 16 + l15;
        const float bo = bias[oseg + ci];
#pragma unroll
        for (int mi = 0; mi < 2; ++mi) {
          const int t0 = t0w + mi * 16 + l4 * 4;
          const u32 w0 = (u32)f2bf(acc[mi][ni][0] + bo) | ((u32)f2bf(acc[mi][ni][1] + bo) << 16);
          const u32 w1 = (u32)f2bf(acc[mi][ni][2] + bo) | ((u32)f2bf(acc[mi][ni][3] + bo) << 16);
          *(uint2*)(Vb + (((size_t)bh * 64 + ci) << 10) + t0) = make_uint2(w0, w1);
        }
      }
    }
  } else {
#pragma unroll
    for (int ni = 0; ni < 4; ++ni) {
      const int o = n0 + wc * 64 + ni * 16 + l15;
      const float bo = bias[o];
#pragma unroll
      for (int mi = 0; mi < 2; ++mi) {
        const int mrow = m0 + wr * 32 + mi * 16 + l4 * 4;
        const int b = mrow >> 10, t0 = mrow & 1023;
        const size_t base = ((size_t)b * 512 + o) * 1024 + t0;
        const float4 xr = *(const float4*)(xres + base);
        float4 ov;
        ov.x = acc[mi][ni][0] + bo + xr.x;
        ov.y = acc[mi][ni][1] + bo + xr.y;
        ov.z = acc[mi][ni][2] + bo + xr.z;
        ov.w = acc[mi][ni][3] + bo + xr.w;
        *(float4*)(out + base) = ov;
      }
    }
  }
}

// ---------------- flash attention: r13 body + 40KB LDS (Ks[3] 2-ahead, Vs[2] 1-ahead) -------
// 256 threads / 4 waves, 64 q-rows/wave, grid 512 -> 4 blocks/CU (was 2 at 48KB).
// Single barrier per tile. vmcnt ledger (loads): queue at tile st top = [K(st),V(st),K(st+1)]
// -> vmcnt(2) forces K(st),V(st) landed, keeps K(st+1) in flight. Buffer overwrites target
// regions last read at tile st-1 (one full barrier ago) — same safety as proven r13.
__global__ __launch_bounds__(256) void k_attn(const u16* __restrict__ Qb,
                                              const u16* __restrict__ Kb,
                                              const u16* __restrict__ Vb,
                                              u16* __restrict__ ht) {
  __shared__ u16 Ks[3][64][64];   // [s][c], rswz chunk-swizzled, 2-ahead
  __shared__ u16 Vs[2][64][64];   // [d][s], rswz chunk-swizzled, 1-ahead
  const int tid = threadIdx.x;
  const int lane = tid & 63, wid = tid >> 6;
  const int l31 = lane & 31, hi = lane >> 5;
  const int fid = blockIdx.x;
  const int bh = fid & 127, qt = fid >> 7;   // qt 0..3
  const int b = bh >> 3, head = bh & 7;
  const int lrow = lane >> 3, lchunk = lane & 7;
  const int rsw = rswz(l31);

  bf16x8 qf0[4], qf1[4];
  {
    const u16* qp0 = Qb + (((size_t)bh * 1024 + qt * 256 + wid * 64 + l31) << 6) + hi * 8;
    const u16* qp1 = qp0 + (32 << 6);
#pragma unroll
    for (int kc = 0; kc < 4; ++kc) {
      qf0[kc] = *(const bf16x8*)(qp0 + kc * 16);
      qf1[kc] = *(const bf16x8*)(qp1 + kc * 16);
    }
  }

  bf16x8 onesf;
#pragma unroll
  for (int i = 0; i < 8; ++i) onesf[i] = (l31 == 0) ? (__bf16)1.0f : (__bf16)0.0f;

  f32x16 ZERO;
#pragma unroll
  for (int r = 0; r < 16; ++r) ZERO[r] = 0.f;

  f32x16 oacc[2][2], osum[2];
#pragma unroll
  for (int g = 0; g < 2; ++g)
#pragma unroll
    for (int r = 0; r < 16; ++r) { oacc[g][0][r] = 0.f; oacc[g][1][r] = 0.f; osum[g][r] = 0.f; }

  auto stageK = [&](int bi, int st) {   // 2 gload16 per thread
    const int s0 = st * 64;
#pragma unroll
    for (int rd = 0; rd < 2; ++rd) {
      const int rbase = wid * 8 + rd * 32;
      const int r = rbase + lrow;
      const int q = lchunk ^ rswz(r);
      gload16(Kb + (((size_t)bh * 1024 + s0 + r) << 6) + q * 8, &Ks[bi][rbase][0]);
    }
  };
  auto stageV = [&](int bi, int st) {   // 2 gload16 per thread
    const int s0 = st * 64;
#pragma unroll
    for (int rd = 0; rd < 2; ++rd) {
      const int rbase = wid * 8 + rd * 32;
      const int r = rbase + lrow;
      const int q = lchunk ^ rswz(r);
      gload16(Vb + (((size_t)bh * 64 + r) << 10) + s0 + q * 8, &Vs[bi][rbase][0]);
    }
  };

  // prologue: V(0), K(0), K(1)  (issue order fixes the vmcnt ledger)
  stageV(0, 0);
  stageK(0, 0);
  stageK(1, 1);

  int bufc = 0;                        // Ks buffer for compute, rotates %3
  for (int st = 0; st < 16; ++st) {
    if (st < 15) {
      asm volatile("s_waitcnt vmcnt(2)" ::: "memory");  // K(st),V(st) landed; K(st+1) in flight
    } else {
      asm volatile("s_waitcnt vmcnt(0)" ::: "memory");
    }
    __builtin_amdgcn_s_barrier();                       // single barrier per tile
    if (st < 15) stageV((st + 1) & 1, st + 1);          // overwrites buf last read at st-1
    if (st < 14) stageK((st + 2) % 3, st + 2);          // overwrites buf last read at st-1
    const int bufv = st & 1;

#pragma unroll
    for (int cb = 0; cb < 2; ++cb) {
      f32x16 sacc0, sacc1;
      __builtin_amdgcn_s_setprio(1);
#pragma unroll
      for (int kc = 0; kc < 4; ++kc) {
        const int r = cb * 32 + l31;
        const bf16x8 kb = *(const bf16x8*)&Ks[bufc][r][((((kc << 1) | hi)) ^ rsw) << 3];
        if (kc == 0) {
          sacc0 = __builtin_amdgcn_mfma_f32_32x32x16_bf16(kb, qf0[kc], ZERO, 0, 0, 0);
          sacc1 = __builtin_amdgcn_mfma_f32_32x32x16_bf16(kb, qf1[kc], ZERO, 0, 0, 0);
        } else {
          sacc0 = __builtin_amdgcn_mfma_f32_32x32x16_bf16(kb, qf0[kc], sacc0, 0, 0, 0);
          sacc1 = __builtin_amdgcn_mfma_f32_32x32x16_bf16(kb, qf1[kc], sacc1, 0, 0, 0);
        }
      }
      __builtin_amdgcn_s_setprio(0);
      float p0[16], p1[16];
#pragma unroll
      for (int r = 0; r < 16; ++r) {
        asm("v_exp_f32 %0, %1" : "=v"(p0[r]) : "v"(sacc0[r]));
        asm("v_exp_f32 %0, %1" : "=v"(p1[r]) : "v"(sacc1[r]));
      }

#pragma unroll
      for (int ksl = 0; ksl < 2; ++ksl) {
        u32 A0, A1, B0, B1, C0, C1, D0, D1;
        asm("v_cvt_pk_bf16_f32 %0, %1, %2" : "=v"(A0) : "v"(p0[8 * ksl + 0]), "v"(p0[8 * ksl + 1]));
        asm("v_cvt_pk_bf16_f32 %0, %1, %2" : "=v"(A1) : "v"(p0[8 * ksl + 2]), "v"(p0[8 * ksl + 3]));
        asm("v_cvt_pk_bf16_f32 %0, %1, %2" : "=v"(B0) : "v"(p0[8 * ksl + 4]), "v"(p0[8 * ksl + 5]));
        asm("v_cvt_pk_bf16_f32 %0, %1, %2" : "=v"(B1) : "v"(p0[8 * ksl + 6]), "v"(p0[8 * ksl + 7]));
        asm volatile("v_permlane32_swap_b32 %0, %1" : "+v"(A0), "+v"(B0));
        asm volatile("v_permlane32_swap_b32 %0, %1" : "+v"(A1), "+v"(B1));
        asm("v_cvt_pk_bf16_f32 %0, %1, %2" : "=v"(C0) : "v"(p1[8 * ksl + 0]), "v"(p1[8 * ksl + 1]));
        asm("v_cvt_pk_bf16_f32 %0, %1, %2" : "=v"(C1) : "v"(p1[8 * ksl + 2]), "v"(p1[8 * ksl + 3]));
        asm("v_cvt_pk_bf16_f32 %0, %1, %2" : "=v"(D0) : "v"(p1[8 * ksl + 4]), "v"(p1[8 * ksl + 5]));
        asm("v_cvt_pk_bf16_f32 %0, %1, %2" : "=v"(D1) : "v"(p1[8 * ksl + 6]), "v"(p1[8 * ksl + 7]));
        asm volatile("v_permlane32_swap_b32 %0, %1" : "+v"(C0), "+v"(D0));
        asm volatile("v_permlane32_swap_b32 %0, %1" : "+v"(C1), "+v"(D1));
        union { u32 w[4]; bf16x8 v; } pa0, pa1;
        pa0.w[0] = A0; pa0.w[1] = A1; pa0.w[2] = B0; pa0.w[3] = B1;
        pa1.w[0] = C0; pa1.w[1] = C1; pa1.w[2] = D0; pa1.w[3] = D1;
        const int ks = cb * 2 + ksl;
        __builtin_amdgcn_s_setprio(1);
#pragma unroll
        for (int db = 0; db < 2; ++db) {
          const int r = db * 32 + l31;
          const bf16x8 vb = *(const bf16x8*)&Vs[bufv][r][((((ks << 1) | hi)) ^ rsw) << 3];
          oacc[0][db] = __builtin_amdgcn_mfma_f32_32x32x16_bf16(pa0.v, vb, oacc[0][db], 0, 0, 0);
          oacc[1][db] = __builtin_amdgcn_mfma_f32_32x32x16_bf16(pa1.v, vb, oacc[1][db], 0, 0, 0);
        }
        osum[0] = __builtin_amdgcn_mfma_f32_32x32x16_bf16(pa0.v, onesf, osum[0], 0, 0, 0);
        osum[1] = __builtin_amdgcn_mfma_f32_32x32x16_bf16(pa1.v, onesf, osum[1], 0, 0, 0);
        __builtin_amdgcn_s_setprio(0);
      }
    }

    bufc = (bufc == 2) ? 0 : bufc + 1;
  }

#pragma unroll
  for (int g = 0; g < 2; ++g) {
    float inv[16];
#pragma unroll
    for (int r = 0; r < 16; ++r) {
      const float ls = __shfl(osum[g][r], lane & 32);
      inv[r] = __builtin_amdgcn_rcpf(ls);
    }
    const int tg = qt * 256 + wid * 64 + g * 32;
#pragma unroll
    for (int db = 0; db < 2; ++db) {
#pragma unroll
      for (int r = 0; r < 16; ++r) {
        const int t = tg + (r & 3) + 8 * (r >> 2) + 4 * hi;
        const int cg = head * 64 + db * 32 + l31;
        ht[((size_t)b * 1024 + t) * 512 + cg] = f2bf(oacc[g][db][r] * inv[r]);
      }
    }
  }
}

extern "C" void kernel_launch(void* const* d_in, const int* in_sizes, int n_in,
                              void* d_out, int out_size, void* d_ws, size_t ws_size,
                              hipStream_t stream) {
  const float* x = (const float*)d_in[0];
  const float* norm_w = (const float*)d_in[1];
  const float* norm_b = (const float*)d_in[2];
  const float* qkv_w = (const float*)d_in[3];
  const float* qkv_b = (const float*)d_in[4];
  const float* proj_w = (const float*)d_in[5];
  const float* proj_b = (const float*)d_in[6];
  float* out = (float*)d_out;

  char* ws = (char*)d_ws;
  u16* qkvw = (u16*)(ws + 0);          // 1,572,864 B
  u16* projw = (u16*)(ws + 1572864);   //   524,288 B
  u16* gnt = (u16*)(ws + 2097152);     // 16,777,216 B  gn_t[b][t][c]
  u16* Qb = (u16*)(ws + 18874368);     // 16,777,216 B  Q[bh][t][ci]
  u16* Kb = (u16*)(ws + 35651584);     // 16,777,216 B  K[bh][s][ci]
  u16* Vb = (u16*)(ws + 52428800);     // 16,777,216 B  V[bh][ci][s]
  u16* ht = (u16*)(ws + 69206016);     // 16,777,216 B  h_t[b][t][c]

  k_prep<<<1536, 256, 0, stream>>>(x, norm_w, norm_b, qkv_w, proj_w, gnt, qkvw, projw);
  k_gemm<0><<<1536, 512, 0, stream>>>(gnt, qkvw, qkv_b, Qb, Kb, Vb, nullptr, nullptr);
  k_attn<<<512, 256, 0, stream>>>(Qb, Kb, Vb, ht);
  k_gemm<1><<<512, 512, 0, stream>>>(ht, projw, proj_b, nullptr, nullptr, nullptr, x, out);
}

// Round 21
// 135.582 us; speedup vs baseline: 1.1102x; 1.1102x over previous
//
#include <hip/hip_runtime.h>

typedef unsigned short u16;
typedef unsigned int u32;
typedef __bf16 bf16x8 __attribute__((ext_vector_type(8)));
typedef float f32x4 __attribute__((ext_vector_type(4)));
typedef float f32x16 __attribute__((ext_vector_type(16)));

#define SCALE_QK 0.35355339059327373f  // 64^-0.25
#define LOG2E 1.4426950408889634f

__device__ __forceinline__ u16 f2bf(float f) {
  u32 u = __float_as_uint(f);
  u += 0x7FFFu + ((u >> 16) & 1u);
  return (u16)(u >> 16);
}

__device__ __forceinline__ void gload16(const u16* g, u16* l) {
  __builtin_amdgcn_global_load_lds((const __attribute__((address_space(1))) void*)g,
                                   (__attribute__((address_space(3))) void*)l, 16, 0, 0);
}

// row swizzle, measured conflict-free for 32-consecutive-row b128 reads at 128B rows (r7: 0)
__device__ __forceinline__ int rswz(int r) { return (r & 7) ^ ((r >> 3) & 3); }

// ---------------- fused prologue: weight converts + GroupNorm in ONE launch ----------------
__global__ __launch_bounds__(256) void k_prep(const float* __restrict__ x,
                                              const float* __restrict__ nw,
                                              const float* __restrict__ nb,
                                              const float* __restrict__ qkvw_f,
                                              const float* __restrict__ projw_f,
                                              u16* __restrict__ gnt,
                                              u16* __restrict__ qkvw,
                                              u16* __restrict__ projw) {
  const int bid = blockIdx.x;
  const int tid = threadIdx.x;

  if (bid >= 512) {
    const float* src = (bid < 1280) ? qkvw_f : projw_f;
    u16* dst = (bid < 1280) ? qkvw : projw;
    const int i = (bid - ((bid < 1280) ? 512 : 1280)) * 256 + tid;
    float4 v = ((const float4*)src)[i];
    u32 lo = (u32)f2bf(v.x) | ((u32)f2bf(v.y) << 16);
    u32 hi = (u32)f2bf(v.z) | ((u32)f2bf(v.w) << 16);
    ((uint2*)dst)[i] = make_uint2(lo, hi);
    return;
  }

  const int b = bid >> 5;
  const int g = bid & 31;
  const float* xg = x + ((size_t)b * 512 + g * 16) * 1024;

  float s = 0.f, ss = 0.f;
#pragma unroll
  for (int it = 0; it < 16; ++it) {
    float4 v = ((const float4*)xg)[tid + it * 256];
    s += v.x + v.y + v.z + v.w;
    ss += v.x * v.x + v.y * v.y + v.z * v.z + v.w * v.w;
  }
#pragma unroll
  for (int off = 32; off >= 1; off >>= 1) {
    s += __shfl_xor(s, off);
    ss += __shfl_xor(ss, off);
  }
  __shared__ float red[8];
  const int wid = tid >> 6, lane = tid & 63;
  if (lane == 0) { red[wid] = s; red[4 + wid] = ss; }
  __syncthreads();
  const float mean = (red[0] + red[1] + red[2] + red[3]) * (1.f / 16384.f);
  const float ex2 = (red[4] + red[5] + red[6] + red[7]) * (1.f / 16384.f);
  const float rstd = rsqrtf(ex2 - mean * mean + 1e-5f);

  const int cp = (tid & 7) * 2, tt = tid >> 3;
  const int c0 = g * 16 + cp;
  const float wc0 = nw[c0] * rstd, bc0 = nb[c0] - mean * wc0;
  const float wc1 = nw[c0 + 1] * rstd, bc1 = nb[c0 + 1] - mean * wc1;
  const float* xc0 = xg + (size_t)cp * 1024;
  const float* xc1 = xc0 + 1024;
  u16* dst = gnt + (size_t)b * 1024 * 512 + c0;
#pragma unroll 8
  for (int t = tt; t < 1024; t += 32) {
    const u32 v0 = f2bf(xc0[t] * wc0 + bc0);
    const u32 v1 = f2bf(xc1[t] * wc1 + bc1);
    *(u32*)(dst + (size_t)t * 512) = v0 | (v1 << 16);
  }
}

// ---------------- GEMM (r15 best-measured): BK=64, counted vmcnt(4), wide-store epilogue ---
template <int MODE>
__global__ __launch_bounds__(512) void k_gemm(const u16* __restrict__ A,
                                              const u16* __restrict__ Bw,
                                              const float* __restrict__ bias,
                                              u16* __restrict__ Qb, u16* __restrict__ Kb,
                                              u16* __restrict__ Vb,
                                              const float* __restrict__ xres,
                                              float* __restrict__ out) {
  __shared__ u16 smem[32768];
  u16* Asb = smem;
  u16* Bsb = smem + 16384;
  const int tid = threadIdx.x;
  const int lane = tid & 63, wid = tid >> 6;
  const int wr = wid >> 1, wc = wid & 1;
  const int fid = blockIdx.x;
  const int m0 = (fid & 127) * 128;
  const int n0 = (fid >> 7) * 128;
  const int l15 = lane & 15, l4 = lane >> 4;
  const f32x4 fzero = {0.f, 0.f, 0.f, 0.f};

  f32x4 acc[2][4];
#pragma unroll
  for (int i = 0; i < 2; ++i)
#pragma unroll
    for (int j = 0; j < 4; ++j) acc[i][j] = fzero;

  const int lrow = (tid & 63) >> 3;
  const int lchunk = tid & 7;

  auto stage = [&](int bi, int kt) {
#pragma unroll
    for (int rd = 0; rd < 2; ++rd) {
      const int rbase = wid * 8 + rd * 64;
      const int r = rbase + lrow;
      const int q = lchunk ^ (r & 7);
      gload16(A + ((size_t)(m0 + r) * 512 + kt * 64 + q * 8), Asb + bi * 8192 + rbase * 64);
      gload16(Bw + ((size_t)(n0 + r) * 512 + kt * 64 + q * 8), Bsb + bi * 8192 + rbase * 64);
    }
  };

  stage(0, 0);
  stage(1, 1);

  for (int kt = 0; kt < 8; ++kt) {
    if (kt < 7) {
      asm volatile("s_waitcnt vmcnt(4)" ::: "memory");
    } else {
      asm volatile("s_waitcnt vmcnt(0)" ::: "memory");
    }
    __builtin_amdgcn_s_barrier();
    const int buf = kt & 1;
#pragma unroll
    for (int ks = 0; ks < 2; ++ks) {
      bf16x8 af[2], bfr[4];
#pragma unroll
      for (int mi = 0; mi < 2; ++mi) {
        const int row = wr * 32 + mi * 16 + l15;
        af[mi] = *(const bf16x8*)&Asb[buf * 8192 + row * 64 + (((((ks << 2) + l4)) ^ (row & 7)) << 3)];
      }
#pragma unroll
      for (int ni = 0; ni < 4; ++ni) {
        const int row = wc * 64 + ni * 16 + l15;
        bfr[ni] = *(const bf16x8*)&Bsb[buf * 8192 + row * 64 + (((((ks << 2) + l4)) ^ (row & 7)) << 3)];
      }
#pragma unroll
      for (int mi = 0; mi < 2; ++mi)
#pragma unroll
        for (int ni = 0; ni < 4; ++ni)
          acc[mi][ni] = __builtin_amdgcn_mfma_f32_16x16x32_bf16(af[mi], bfr[ni], acc[mi][ni], 0, 0, 0);
    }
    asm volatile("s_waitcnt lgkmcnt(0)" ::: "memory");
    __builtin_amdgcn_sched_barrier(0);
    __builtin_amdgcn_s_barrier();
    if (kt < 6) stage(buf, kt + 2);
  }

  if (MODE == 0) {
    const int oseg = n0 + wc * 64;
    const int h = oseg / 192;
    const int typ = (oseg - h * 192) >> 6;
    const int b = m0 >> 10;
    const int bh = b * 8 + h;
    const int t0w = (m0 & 1023) + wr * 32;
    if (typ < 2) {
      const float sc = (typ == 0) ? (SCALE_QK * LOG2E) : SCALE_QK;
      u16* scr = smem + wid * 4096;
#pragma unroll
      for (int ni = 0; ni < 4; ++ni) {
        const int ol = ni * 16 + l15;
        const float bo = bias[oseg + ol];
#pragma unroll
        for (int mi = 0; mi < 2; ++mi) {
#pragma unroll
          for (int jj = 0; jj < 4; ++jj) {
            const int tl = mi * 16 + l4 * 4 + jj;
            scr[tl * 72 + ol] = f2bf((acc[mi][ni][jj] + bo) * sc);
          }
        }
      }
      asm volatile("s_waitcnt lgkmcnt(0)" ::: "memory");
      u16* qk = (typ == 0) ? Qb : Kb;
      const int tr = lane & 31;
#pragma unroll
      for (int i = 0; i < 4; ++i) {
        const int ch = (lane >> 5) * 4 + i;
        const uint4 v = *(const uint4*)&scr[tr * 72 + ch * 8];
        *(uint4*)(qk + (((size_t)bh * 1024 + t0w + tr) << 6) + ch * 8) = v;
      }
    } else {
#pragma unroll
      for (int ni = 0; ni < 4; ++ni) {
        const int ci = ni * 16 + l15;
        const float bo = bias[oseg + ci];
#pragma unroll
        for (int mi = 0; mi < 2; ++mi) {
          const int t0 = t0w + mi * 16 + l4 * 4;
          const u32 w0 = (u32)f2bf(acc[mi][ni][0] + bo) | ((u32)f2bf(acc[mi][ni][1] + bo) << 16);
          const u32 w1 = (u32)f2bf(acc[mi][ni][2] + bo) | ((u32)f2bf(acc[mi][ni][3] + bo) << 16);
          *(uint2*)(Vb + (((size_t)bh * 64 + ci) << 10) + t0) = make_uint2(w0, w1);
        }
      }
    }
  } else {
#pragma unroll
    for (int ni = 0; ni < 4; ++ni) {
      const int o = n0 + wc * 64 + ni * 16 + l15;
      const float bo = bias[o];
#pragma unroll
      for (int mi = 0; mi < 2; ++mi) {
        const int mrow = m0 + wr * 32 + mi * 16 + l4 * 4;
        const int b = mrow >> 10, t0 = mrow & 1023;
        const size_t base = ((size_t)b * 512 + o) * 1024 + t0;
        const float4 xr = *(const float4*)(xres + base);
        float4 ov;
        ov.x = acc[mi][ni][0] + bo + xr.x;
        ov.y = acc[mi][ni][1] + bo + xr.y;
        ov.z = acc[mi][ni][2] + bo + xr.z;
        ov.w = acc[mi][ni][3] + bo + xr.w;
        *(float4*)(out + base) = ov;
      }
    }
  }
}

// ---------------- flash attention (r13 best-measured, verbatim) ----------------------------
// 256 threads / 4 waves, 64 q-rows/wave (2 Q-groups share each K/V read), grid 512.
// 3 LDS buffers, ONE barrier per tile, counted vmcnt(4), ZERO-C first MFMA, rcp epilogue.
__global__ __launch_bounds__(256) void k_attn(const u16* __restrict__ Qb,
                                              const u16* __restrict__ Kb,
                                              const u16* __restrict__ Vb,
                                              u16* __restrict__ ht) {
  __shared__ u16 Ks[3][64][64];   // [s][c], rswz chunk-swizzled
  __shared__ u16 Vs[3][64][64];   // [d][s], rswz chunk-swizzled
  const int tid = threadIdx.x;
  const int lane = tid & 63, wid = tid >> 6;
  const int l31 = lane & 31, hi = lane >> 5;
  const int fid = blockIdx.x;
  const int bh = fid & 127, qt = fid >> 7;   // qt 0..3
  const int b = bh >> 3, head = bh & 7;
  const int lrow = lane >> 3, lchunk = lane & 7;
  const int rsw = rswz(l31);

  bf16x8 qf0[4], qf1[4];
  {
    const u16* qp0 = Qb + (((size_t)bh * 1024 + qt * 256 + wid * 64 + l31) << 6) + hi * 8;
    const u16* qp1 = qp0 + (32 << 6);
#pragma unroll
    for (int kc = 0; kc < 4; ++kc) {
      qf0[kc] = *(const bf16x8*)(qp0 + kc * 16);
      qf1[kc] = *(const bf16x8*)(qp1 + kc * 16);
    }
  }

  bf16x8 onesf;
#pragma unroll
  for (int i = 0; i < 8; ++i) onesf[i] = (l31 == 0) ? (__bf16)1.0f : (__bf16)0.0f;

  f32x16 ZERO;
#pragma unroll
  for (int r = 0; r < 16; ++r) ZERO[r] = 0.f;

  f32x16 oacc[2][2], osum[2];
#pragma unroll
  for (int g = 0; g < 2; ++g)
#pragma unroll
    for (int r = 0; r < 16; ++r) { oacc[g][0][r] = 0.f; oacc[g][1][r] = 0.f; osum[g][r] = 0.f; }

  auto stageKV = [&](int bi, int st) {   // 4 gload16 per thread
    const int s0 = st * 64;
#pragma unroll
    for (int rd = 0; rd < 2; ++rd) {
      const int rbase = wid * 8 + rd * 32;
      const int r = rbase + lrow;
      const int q = lchunk ^ rswz(r);
      gload16(Kb + (((size_t)bh * 1024 + s0 + r) << 6) + q * 8, &Ks[bi][rbase][0]);
      gload16(Vb + (((size_t)bh * 64 + r) << 10) + s0 + q * 8, &Vs[bi][rbase][0]);
    }
  };

  stageKV(0, 0);
  stageKV(1, 1);

  int bufc = 0, bufs = 2;
  for (int st = 0; st < 16; ++st) {
    if (st < 15) {
      asm volatile("s_waitcnt vmcnt(4)" ::: "memory");
    } else {
      asm volatile("s_waitcnt vmcnt(0)" ::: "memory");
    }
    __builtin_amdgcn_s_barrier();
    if (st < 14) stageKV(bufs, st + 2);

#pragma unroll
    for (int cb = 0; cb < 2; ++cb) {
      f32x16 sacc0, sacc1;
      __builtin_amdgcn_s_setprio(1);
#pragma unroll
      for (int kc = 0; kc < 4; ++kc) {
        const int r = cb * 32 + l31;
        const bf16x8 kb = *(const bf16x8*)&Ks[bufc][r][((((kc << 1) | hi)) ^ rsw) << 3];
        if (kc == 0) {
          sacc0 = __builtin_amdgcn_mfma_f32_32x32x16_bf16(kb, qf0[kc], ZERO, 0, 0, 0);
          sacc1 = __builtin_amdgcn_mfma_f32_32x32x16_bf16(kb, qf1[kc], ZERO, 0, 0, 0);
        } else {
          sacc0 = __builtin_amdgcn_mfma_f32_32x32x16_bf16(kb, qf0[kc], sacc0, 0, 0, 0);
          sacc1 = __builtin_amdgcn_mfma_f32_32x32x16_bf16(kb, qf1[kc], sacc1, 0, 0, 0);
        }
      }
      __builtin_amdgcn_s_setprio(0);
      float p0[16], p1[16];
#pragma unroll
      for (int r = 0; r < 16; ++r) {
        asm("v_exp_f32 %0, %1" : "=v"(p0[r]) : "v"(sacc0[r]));
        asm("v_exp_f32 %0, %1" : "=v"(p1[r]) : "v"(sacc1[r]));
      }

#pragma unroll
      for (int ksl = 0; ksl < 2; ++ksl) {
        u32 A0, A1, B0, B1, C0, C1, D0, D1;
        asm("v_cvt_pk_bf16_f32 %0, %1, %2" : "=v"(A0) : "v"(p0[8 * ksl + 0]), "v"(p0[8 * ksl + 1]));
        asm("v_cvt_pk_bf16_f32 %0, %1, %2" : "=v"(A1) : "v"(p0[8 * ksl + 2]), "v"(p0[8 * ksl + 3]));
        asm("v_cvt_pk_bf16_f32 %0, %1, %2" : "=v"(B0) : "v"(p0[8 * ksl + 4]), "v"(p0[8 * ksl + 5]));
        asm("v_cvt_pk_bf16_f32 %0, %1, %2" : "=v"(B1) : "v"(p0[8 * ksl + 6]), "v"(p0[8 * ksl + 7]));
        asm volatile("v_permlane32_swap_b32 %0, %1" : "+v"(A0), "+v"(B0));
        asm volatile("v_permlane32_swap_b32 %0, %1" : "+v"(A1), "+v"(B1));
        asm("v_cvt_pk_bf16_f32 %0, %1, %2" : "=v"(C0) : "v"(p1[8 * ksl + 0]), "v"(p1[8 * ksl + 1]));
        asm("v_cvt_pk_bf16_f32 %0, %1, %2" : "=v"(C1) : "v"(p1[8 * ksl + 2]), "v"(p1[8 * ksl + 3]));
        asm("v_cvt_pk_bf16_f32 %0, %1, %2" : "=v"(D0) : "v"(p1[8 * ksl + 4]), "v"(p1[8 * ksl + 5]));
        asm("v_cvt_pk_bf16_f32 %0, %1, %2" : "=v"(D1) : "v"(p1[8 * ksl + 6]), "v"(p1[8 * ksl + 7]));
        asm volatile("v_permlane32_swap_b32 %0, %1" : "+v"(C0), "+v"(D0));
        asm volatile("v_permlane32_swap_b32 %0, %1" : "+v"(C1), "+v"(D1));
        union { u32 w[4]; bf16x8 v; } pa0, pa1;
        pa0.w[0] = A0; pa0.w[1] = A1; pa0.w[2] = B0; pa0.w[3] = B1;
        pa1.w[0] = C0; pa1.w[1] = C1; pa1.w[2] = D0; pa1.w[3] = D1;
        const int ks = cb * 2 + ksl;
        __builtin_amdgcn_s_setprio(1);
#pragma unroll
        for (int db = 0; db < 2; ++db) {
          const int r = db * 32 + l31;
          const bf16x8 vb = *(const bf16x8*)&Vs[bufc][r][((((ks << 1) | hi)) ^ rsw) << 3];
          oacc[0][db] = __builtin_amdgcn_mfma_f32_32x32x16_bf16(pa0.v, vb, oacc[0][db], 0, 0, 0);
          oacc[1][db] = __builtin_amdgcn_mfma_f32_32x32x16_bf16(pa1.v, vb, oacc[1][db], 0, 0, 0);
        }
        osum[0] = __builtin_amdgcn_mfma_f32_32x32x16_bf16(pa0.v, onesf, osum[0], 0, 0, 0);
        osum[1] = __builtin_amdgcn_mfma_f32_32x32x16_bf16(pa1.v, onesf, osum[1], 0, 0, 0);
        __builtin_amdgcn_s_setprio(0);
      }
    }

    bufc = (bufc == 2) ? 0 : bufc + 1;
    bufs = (bufs == 2) ? 0 : bufs + 1;
  }

#pragma unroll
  for (int g = 0; g < 2; ++g) {
    float inv[16];
#pragma unroll
    for (int r = 0; r < 16; ++r) {
      const float ls = __shfl(osum[g][r], lane & 32);
      inv[r] = __builtin_amdgcn_rcpf(ls);
    }
    const int tg = qt * 256 + wid * 64 + g * 32;
#pragma unroll
    for (int db = 0; db < 2; ++db) {
#pragma unroll
      for (int r = 0; r < 16; ++r) {
        const int t = tg + (r & 3) + 8 * (r >> 2) + 4 * hi;
        const int cg = head * 64 + db * 32 + l31;
        ht[((size_t)b * 1024 + t) * 512 + cg] = f2bf(oacc[g][db][r] * inv[r]);
      }
    }
  }
}

extern "C" void kernel_launch(void* const* d_in, const int* in_sizes, int n_in,
                              void* d_out, int out_size, void* d_ws, size_t ws_size,
                              hipStream_t stream) {
  const float* x = (const float*)d_in[0];
  const float* norm_w = (const float*)d_in[1];
  const float* norm_b = (const float*)d_in[2];
  const float* qkv_w = (const float*)d_in[3];
  const float* qkv_b = (const float*)d_in[4];
  const float* proj_w = (const float*)d_in[5];
  const float* proj_b = (const float*)d_in[6];
  float* out = (float*)d_out;

  char* ws = (char*)d_ws;
  u16* qkvw = (u16*)(ws + 0);          // 1,572,864 B
  u16* projw = (u16*)(ws + 1572864);   //   524,288 B
  u16* gnt = (u16*)(ws + 2097152);     // 16,777,216 B  gn_t[b][t][c]
  u16* Qb = (u16*)(ws + 18874368);     // 16,777,216 B  Q[bh][t][ci]
  u16* Kb = (u16*)(ws + 35651584);     // 16,777,216 B  K[bh][s][ci]
  u16* Vb = (u16*)(ws + 52428800);     // 16,777,216 B  V[bh][ci][s]
  u16* ht = (u16*)(ws + 69206016);     // 16,777,216 B  h_t[b][t][c]

  k_prep<<<1536, 256, 0, stream>>>(x, norm_w, norm_b, qkv_w, proj_w, gnt, qkvw, projw);
  k_gemm<0><<<1536, 512, 0, stream>>>(gnt, qkvw, qkv_b, Qb, Kb, Vb, nullptr, nullptr);
  k_attn<<<512, 256, 0, stream>>>(Qb, Kb, Vb, ht);
  k_gemm<1><<<512, 512, 0, stream>>>(ht, projw, proj_b, nullptr, nullptr, nullptr, x, out);
}